// Round 2
// baseline (130.358 us; speedup 1.0000x reference)
//
#include <hip/hip_runtime.h>

// Chamfer distance: srcs, tgts [B=8, D=3, N=4096] f32 -> scalar f32
//   out = mean_{b,j} min_i |s_i - t_j|^2  +  mean_{b,i} min_j |s_i - t_j|^2

#define CD_B 8
#define CD_N 4096
#define BLK 256
#define UNR 8

__global__ void cd_zero(float* out) { out[0] = 0.0f; }

__global__ __launch_bounds__(BLK) void cd_min_kernel(
    const float* __restrict__ srcs, const float* __restrict__ tgts,
    float* __restrict__ out) {
  // blockIdx.x = dir*B*(N/BLK) + b*(N/BLK) + chunk
  const int bid   = blockIdx.x;
  const int chunk = bid & (CD_N / BLK - 1);          // 16 chunks
  const int b     = (bid >> 4) & (CD_B - 1);
  const int dir   = bid >> 7;

  const float* qset = dir ? tgts : srcs;  // query points (we min over the other set)
  const float* tset = dir ? srcs : tgts;
  const float* qb = qset + b * 3 * CD_N;
  const float* tb = tset + b * 3 * CD_N;

  // Stage target set as (x, y, z, |t|^2) float4 — exactly 64 KiB LDS.
  __shared__ float4 T[CD_N];
  __shared__ float wsum[BLK / 64];
  const int tid = threadIdx.x;
  for (int j = tid; j < CD_N; j += BLK) {
    float x = tb[j];
    float y = tb[CD_N + j];
    float z = tb[2 * CD_N + j];
    T[j] = make_float4(x, y, z, x * x + y * y + z * z);
  }
  __syncthreads();

  const int qi = chunk * BLK + tid;
  const float sx = qb[qi];
  const float sy = qb[CD_N + qi];
  const float sz = qb[2 * CD_N + qi];

  // min_j (|t_j|^2 - 2 s.t_j); add |s|^2 afterwards.
  // 8 independent accumulators -> no serial fmin dependency chain.
  float mm[UNR];
#pragma unroll
  for (int u = 0; u < UNR; ++u) mm[u] = 3.4e38f;

  for (int j = 0; j < CD_N; j += UNR) {
#pragma unroll
    for (int u = 0; u < UNR; ++u) {
      float4 p = T[j + u];
      float st = fmaf(sx, p.x, fmaf(sy, p.y, sz * p.z));
      mm[u] = fminf(mm[u], fmaf(-2.0f, st, p.w));
    }
  }
  float m = fminf(fminf(fminf(mm[0], mm[1]), fminf(mm[2], mm[3])),
                  fminf(fminf(mm[4], mm[5]), fminf(mm[6], mm[7])));
  m += sx * sx + sy * sy + sz * sz;

  // wave64 shuffle reduction (sum of per-query mins)
  for (int off = 32; off; off >>= 1) m += __shfl_down(m, off, 64);
  const int wid = tid >> 6;
  if ((tid & 63) == 0) wsum[wid] = m;
  __syncthreads();
  if (tid == 0) {
    float s = wsum[0] + wsum[1] + wsum[2] + wsum[3];
    atomicAdd(out, s * (1.0f / (float)(CD_B * CD_N)));
  }
}

extern "C" void kernel_launch(void* const* d_in, const int* in_sizes, int n_in,
                              void* d_out, int out_size, void* d_ws, size_t ws_size,
                              hipStream_t stream) {
  const float* srcs = (const float*)d_in[0];
  const float* tgts = (const float*)d_in[1];
  float* out = (float*)d_out;

  cd_zero<<<1, 1, 0, stream>>>(out);
  const int nblocks = 2 * CD_B * (CD_N / BLK);  // 256
  cd_min_kernel<<<nblocks, BLK, 0, stream>>>(srcs, tgts, out);
}

// Round 3
// 86.838 us; speedup vs baseline: 1.5012x; 1.5012x over previous
//
#include <hip/hip_runtime.h>

// Chamfer distance: srcs, tgts [B=8, D=3, N=4096] f32 -> scalar f32
//   out = mean_{b,j} min_i |s_i - t_j|^2  +  mean_{b,i} min_j |s_i - t_j|^2
//
// Round 3: LDS-pipe-bound fix. 8 queries/thread amortize each broadcast
// ds_read_b128 over 80 VALU cycles; target set split 16-ways to restore
// grid parallelism (512 blocks = 2 waves/SIMD). Partial mins -> ws,
// second kernel combines.

#define CD_B 8
#define CD_N 4096
#define BLK 256
#define TCH 16               // target chunks
#define TPB (CD_N / TCH)     // 256 targets per block
#define QQ 8                 // queries per thread
#define QPB (BLK * QQ)       // 2048 queries per block
#define QCH (CD_N / QPB)     // 2 query chunks
#define NQ (2 * CD_B * CD_N) // 65536 total queries

// ws layout: float ws[TCH][NQ]  (4 MB)
__global__ __launch_bounds__(BLK) void cd_partial(
    const float* __restrict__ srcs, const float* __restrict__ tgts,
    float* __restrict__ ws, float* __restrict__ out) {
  const int bid = blockIdx.x;              // 512 blocks
  const int tc  = bid & (TCH - 1);         // 4 bits
  const int qc  = (bid >> 4) & (QCH - 1);  // 1 bit
  const int b   = (bid >> 5) & (CD_B - 1); // 3 bits
  const int dir = bid >> 8;                // 1 bit

  const float* qb = (dir ? tgts : srcs) + b * 3 * CD_N;
  const float* tb = (dir ? srcs : tgts) + b * 3 * CD_N;

  __shared__ float4 T[TPB];  // 4 KiB
  const int tid = threadIdx.x;
  {
    int gj = tc * TPB + tid;               // one target per thread
    float x = tb[gj], y = tb[CD_N + gj], z = tb[2 * CD_N + gj];
    T[tid] = make_float4(x, y, z, x * x + y * y + z * z);
  }
  if (bid == 0 && tid == 0) out[0] = 0.0f;  // stream-ordered before cd_reduce
  __syncthreads();

  float sx[QQ], sy[QQ], sz[QQ];
  const int q0 = qc * QPB + tid;
#pragma unroll
  for (int qq = 0; qq < QQ; ++qq) {
    int q = q0 + qq * BLK;
    sx[qq] = qb[q];
    sy[qq] = qb[CD_N + q];
    sz[qq] = qb[2 * CD_N + q];
  }

  float mm[QQ];
#pragma unroll
  for (int qq = 0; qq < QQ; ++qq) mm[qq] = 3.4e38f;

  for (int j = 0; j < TPB; j += 2) {
#pragma unroll
    for (int u = 0; u < 2; ++u) {
      float4 p = T[j + u];
#pragma unroll
      for (int qq = 0; qq < QQ; ++qq) {
        float st = fmaf(sx[qq], p.x, fmaf(sy[qq], p.y, sz[qq] * p.z));
        mm[qq] = fminf(mm[qq], fmaf(-2.0f, st, p.w));
      }
    }
  }

  const int gqbase = (dir * CD_B + b) * CD_N + qc * QPB + tid;
  float* wrow = ws + (size_t)tc * NQ;
#pragma unroll
  for (int qq = 0; qq < QQ; ++qq) {
    float ssq = fmaf(sx[qq], sx[qq], fmaf(sy[qq], sy[qq], sz[qq] * sz[qq]));
    wrow[gqbase + qq * BLK] = mm[qq] + ssq;  // full min-dist partial
  }
}

__global__ __launch_bounds__(BLK) void cd_reduce(
    const float* __restrict__ ws, float* __restrict__ out) {
  const int q = blockIdx.x * BLK + threadIdx.x;  // 65536 threads
  float m = ws[q];
#pragma unroll
  for (int tc = 1; tc < TCH; ++tc) m = fminf(m, ws[(size_t)tc * NQ + q]);

  // wave64 sum reduction of per-query mins
  for (int off = 32; off; off >>= 1) m += __shfl_down(m, off, 64);
  __shared__ float wsum[BLK / 64];
  if ((threadIdx.x & 63) == 0) wsum[threadIdx.x >> 6] = m;
  __syncthreads();
  if (threadIdx.x == 0) {
    float s = (wsum[0] + wsum[1]) + (wsum[2] + wsum[3]);
    atomicAdd(out, s * (1.0f / (float)(CD_B * CD_N)));
  }
}

extern "C" void kernel_launch(void* const* d_in, const int* in_sizes, int n_in,
                              void* d_out, int out_size, void* d_ws, size_t ws_size,
                              hipStream_t stream) {
  const float* srcs = (const float*)d_in[0];
  const float* tgts = (const float*)d_in[1];
  float* out = (float*)d_out;
  float* ws = (float*)d_ws;  // needs TCH*NQ*4 = 4 MB

  cd_partial<<<2 * CD_B * QCH * TCH, BLK, 0, stream>>>(srcs, tgts, ws, out);
  cd_reduce<<<NQ / BLK, BLK, 0, stream>>>(ws, out);
}

// Round 4
// 86.476 us; speedup vs baseline: 1.5075x; 1.0042x over previous
//
#include <hip/hip_runtime.h>

// Chamfer distance: srcs, tgts [B=8, D=3, N=4096] f32 -> scalar f32
//   out = mean_{b,j} min_i |s_i - t_j|^2  +  mean_{b,i} min_j |s_i - t_j|^2
//
// Round 4: 4 waves/SIMD (TCH=32 -> 1024 blocks) for latency hiding;
// pair-merged min (v_min3 fusion) cuts 5 -> 4.5 VALU/pair.
// Harness poison of d_ws (~41 us) is an uncontrollable floor in dur_us.

#define CD_B 8
#define CD_N 4096
#define BLK 256
#define TCH 32               // target chunks
#define TPB (CD_N / TCH)     // 128 targets per block
#define QQ 8                 // queries per thread
#define QPB (BLK * QQ)       // 2048 queries per block
#define QCH (CD_N / QPB)     // 2 query chunks
#define NQ (2 * CD_B * CD_N) // 65536 total queries

// ws layout: float ws[TCH][NQ]  (8 MB)
__global__ __launch_bounds__(BLK) void cd_partial(
    const float* __restrict__ srcs, const float* __restrict__ tgts,
    float* __restrict__ ws, float* __restrict__ out) {
  const int bid = blockIdx.x;               // 1024 blocks
  const int tc  = bid & (TCH - 1);          // 5 bits
  const int qc  = (bid >> 5) & (QCH - 1);   // 1 bit
  const int b   = (bid >> 6) & (CD_B - 1);  // 3 bits
  const int dir = bid >> 9;                 // 1 bit

  const float* qb = (dir ? tgts : srcs) + b * 3 * CD_N;
  const float* tb = (dir ? srcs : tgts) + b * 3 * CD_N;

  __shared__ float4 T[TPB];  // 2 KiB
  const int tid = threadIdx.x;
  if (tid < TPB) {
    int gj = tc * TPB + tid;
    float x = tb[gj], y = tb[CD_N + gj], z = tb[2 * CD_N + gj];
    T[tid] = make_float4(x, y, z, x * x + y * y + z * z);
  }
  if (bid == 0 && tid == 0) out[0] = 0.0f;  // stream-ordered before cd_reduce
  __syncthreads();

  float sx[QQ], sy[QQ], sz[QQ];
  const int q0 = qc * QPB + tid;
#pragma unroll
  for (int qq = 0; qq < QQ; ++qq) {
    int q = q0 + qq * BLK;
    sx[qq] = qb[q];
    sy[qq] = qb[CD_N + q];
    sz[qq] = qb[2 * CD_N + q];
  }

  float mm[QQ];
#pragma unroll
  for (int qq = 0; qq < QQ; ++qq) mm[qq] = 3.4e38f;

  for (int j = 0; j < TPB; j += 2) {
    float4 p0 = T[j];
    float4 p1 = T[j + 1];
#pragma unroll
    for (int qq = 0; qq < QQ; ++qq) {
      float st0 = fmaf(sx[qq], p0.x, fmaf(sy[qq], p0.y, sz[qq] * p0.z));
      float st1 = fmaf(sx[qq], p1.x, fmaf(sy[qq], p1.y, sz[qq] * p1.z));
      float v0 = fmaf(-2.0f, st0, p0.w);
      float v1 = fmaf(-2.0f, st1, p1.w);
      mm[qq] = fminf(mm[qq], fminf(v0, v1));  // -> v_min3_f32
    }
  }

  const int gqbase = (dir * CD_B + b) * CD_N + qc * QPB + tid;
  float* wrow = ws + (size_t)tc * NQ;
#pragma unroll
  for (int qq = 0; qq < QQ; ++qq) {
    float ssq = fmaf(sx[qq], sx[qq], fmaf(sy[qq], sy[qq], sz[qq] * sz[qq]));
    wrow[gqbase + qq * BLK] = mm[qq] + ssq;  // full min-dist partial
  }
}

__global__ __launch_bounds__(BLK) void cd_reduce(
    const float* __restrict__ ws, float* __restrict__ out) {
  const int q = blockIdx.x * BLK + threadIdx.x;  // 65536 threads
  float m0 = ws[q];
  float m1 = ws[(size_t)1 * NQ + q];
#pragma unroll
  for (int tc = 2; tc < TCH; tc += 2) {
    m0 = fminf(m0, ws[(size_t)tc * NQ + q]);
    m1 = fminf(m1, ws[(size_t)(tc + 1) * NQ + q]);
  }
  float m = fminf(m0, m1);

  // wave64 sum reduction of per-query mins
  for (int off = 32; off; off >>= 1) m += __shfl_down(m, off, 64);
  __shared__ float wsum[BLK / 64];
  if ((threadIdx.x & 63) == 0) wsum[threadIdx.x >> 6] = m;
  __syncthreads();
  if (threadIdx.x == 0) {
    float s = (wsum[0] + wsum[1]) + (wsum[2] + wsum[3]);
    atomicAdd(out, s * (1.0f / (float)(CD_B * CD_N)));
  }
}

extern "C" void kernel_launch(void* const* d_in, const int* in_sizes, int n_in,
                              void* d_out, int out_size, void* d_ws, size_t ws_size,
                              hipStream_t stream) {
  const float* srcs = (const float*)d_in[0];
  const float* tgts = (const float*)d_in[1];
  float* out = (float*)d_out;
  float* ws = (float*)d_ws;  // needs TCH*NQ*4 = 8 MB

  cd_partial<<<2 * CD_B * QCH * TCH, BLK, 0, stream>>>(srcs, tgts, ws, out);
  cd_reduce<<<NQ / BLK, BLK, 0, stream>>>(ws, out);
}

// Round 5
// 82.871 us; speedup vs baseline: 1.5730x; 1.0435x over previous
//
#include <hip/hip_runtime.h>

// Chamfer distance: srcs, tgts [B=8, D=3, N=4096] f32 -> scalar f32
//   out = mean_{b,j} min_i |s_i - t_j|^2  +  mean_{b,i} min_j |s_i - t_j|^2
//
// Round 5: (a) LDS stages (-2x,-2y,-2z,|t|^2) so each pair is 3 fma
// (+ shared v_min3), 5 -> 3.5 inst/pair; (b) explicit 4-target register
// prefetch hides the per-iteration LDS round-trip; (c) inline-asm
// v_min3_f32 (fminf pairs don't fuse without fast-math).
// Fixed harness floor: d_ws re-poison ~41.5 us is inside the timed region.

#define CD_B 8
#define CD_N 4096
#define BLK 256
#define TCH 32               // target chunks
#define TPB (CD_N / TCH)     // 128 targets per block
#define QQ 8                 // queries per thread
#define QPB (BLK * QQ)       // 2048 queries per block
#define QCH (CD_N / QPB)     // 2 query chunks
#define NQ (2 * CD_B * CD_N) // 65536 total queries

__device__ __forceinline__ float min3f(float m, float a, float b) {
  asm("v_min3_f32 %0, %1, %2, %0" : "+v"(m) : "v"(a), "v"(b));
  return m;
}

// ws layout: float ws[TCH][NQ]  (8 MB)
__global__ __launch_bounds__(BLK) void cd_partial(
    const float* __restrict__ srcs, const float* __restrict__ tgts,
    float* __restrict__ ws, float* __restrict__ out) {
  const int bid = blockIdx.x;               // 1024 blocks
  const int tc  = bid & (TCH - 1);          // 5 bits
  const int qc  = (bid >> 5) & (QCH - 1);   // 1 bit
  const int b   = (bid >> 6) & (CD_B - 1);  // 3 bits
  const int dir = bid >> 9;                 // 1 bit

  const float* qb = (dir ? tgts : srcs) + b * 3 * CD_N;
  const float* tb = (dir ? srcs : tgts) + b * 3 * CD_N;

  // T[j] = (-2x, -2y, -2z, |t|^2)
  __shared__ float4 T[TPB];  // 2 KiB
  const int tid = threadIdx.x;
  if (tid < TPB) {
    int gj = tc * TPB + tid;
    float x = tb[gj], y = tb[CD_N + gj], z = tb[2 * CD_N + gj];
    float w = fmaf(x, x, fmaf(y, y, z * z));
    T[tid] = make_float4(-2.0f * x, -2.0f * y, -2.0f * z, w);
  }
  if (bid == 0 && tid == 0) out[0] = 0.0f;  // stream-ordered before cd_reduce
  __syncthreads();

  float sx[QQ], sy[QQ], sz[QQ];
  const int q0 = qc * QPB + tid;
#pragma unroll
  for (int qq = 0; qq < QQ; ++qq) {
    int q = q0 + qq * BLK;
    sx[qq] = qb[q];
    sy[qq] = qb[CD_N + q];
    sz[qq] = qb[2 * CD_N + q];
  }

  float mm[QQ];
#pragma unroll
  for (int qq = 0; qq < QQ; ++qq) mm[qq] = 3.4e38f;

  // 4-target software pipeline: load next 4 while computing current 4.
  float4 c0 = T[0], c1 = T[1], c2 = T[2], c3 = T[3];
#pragma unroll 2
  for (int j = 4; j < TPB; j += 4) {
    float4 n0 = T[j], n1 = T[j + 1], n2 = T[j + 2], n3 = T[j + 3];
#pragma unroll
    for (int qq = 0; qq < QQ; ++qq) {
      float v0 = fmaf(sx[qq], c0.x, fmaf(sy[qq], c0.y, fmaf(sz[qq], c0.z, c0.w)));
      float v1 = fmaf(sx[qq], c1.x, fmaf(sy[qq], c1.y, fmaf(sz[qq], c1.z, c1.w)));
      float v2 = fmaf(sx[qq], c2.x, fmaf(sy[qq], c2.y, fmaf(sz[qq], c2.z, c2.w)));
      float v3 = fmaf(sx[qq], c3.x, fmaf(sy[qq], c3.y, fmaf(sz[qq], c3.z, c3.w)));
      mm[qq] = min3f(mm[qq], v0, v1);
      mm[qq] = min3f(mm[qq], v2, v3);
    }
    c0 = n0; c1 = n1; c2 = n2; c3 = n3;
  }
#pragma unroll
  for (int qq = 0; qq < QQ; ++qq) {
    float v0 = fmaf(sx[qq], c0.x, fmaf(sy[qq], c0.y, fmaf(sz[qq], c0.z, c0.w)));
    float v1 = fmaf(sx[qq], c1.x, fmaf(sy[qq], c1.y, fmaf(sz[qq], c1.z, c1.w)));
    float v2 = fmaf(sx[qq], c2.x, fmaf(sy[qq], c2.y, fmaf(sz[qq], c2.z, c2.w)));
    float v3 = fmaf(sx[qq], c3.x, fmaf(sy[qq], c3.y, fmaf(sz[qq], c3.z, c3.w)));
    mm[qq] = min3f(mm[qq], v0, v1);
    mm[qq] = min3f(mm[qq], v2, v3);
  }

  const int gqbase = (dir * CD_B + b) * CD_N + qc * QPB + tid;
  float* wrow = ws + (size_t)tc * NQ;
#pragma unroll
  for (int qq = 0; qq < QQ; ++qq) {
    float ssq = fmaf(sx[qq], sx[qq], fmaf(sy[qq], sy[qq], sz[qq] * sz[qq]));
    wrow[gqbase + qq * BLK] = mm[qq] + ssq;  // full min-dist partial
  }
}

__global__ __launch_bounds__(BLK) void cd_reduce(
    const float* __restrict__ ws, float* __restrict__ out) {
  const int q = blockIdx.x * BLK + threadIdx.x;  // 65536 threads
  float m0 = ws[q];
  float m1 = ws[(size_t)1 * NQ + q];
#pragma unroll
  for (int tc = 2; tc < TCH; tc += 2) {
    m0 = fminf(m0, ws[(size_t)tc * NQ + q]);
    m1 = fminf(m1, ws[(size_t)(tc + 1) * NQ + q]);
  }
  float m = fminf(m0, m1);

  // wave64 sum reduction of per-query mins
  for (int off = 32; off; off >>= 1) m += __shfl_down(m, off, 64);
  __shared__ float wsum[BLK / 64];
  if ((threadIdx.x & 63) == 0) wsum[threadIdx.x >> 6] = m;
  __syncthreads();
  if (threadIdx.x == 0) {
    float s = (wsum[0] + wsum[1]) + (wsum[2] + wsum[3]);
    atomicAdd(out, s * (1.0f / (float)(CD_B * CD_N)));
  }
}

extern "C" void kernel_launch(void* const* d_in, const int* in_sizes, int n_in,
                              void* d_out, int out_size, void* d_ws, size_t ws_size,
                              hipStream_t stream) {
  const float* srcs = (const float*)d_in[0];
  const float* tgts = (const float*)d_in[1];
  float* out = (float*)d_out;
  float* ws = (float*)d_ws;  // needs TCH*NQ*4 = 8 MB

  cd_partial<<<2 * CD_B * QCH * TCH, BLK, 0, stream>>>(srcs, tgts, ws, out);
  cd_reduce<<<NQ / BLK, BLK, 0, stream>>>(ws, out);
}